// Round 4
// baseline (113.526 us; speedup 1.0000x reference)
//
#include <hip/hip_runtime.h>

// PlanarFlow: x = z + tanh(z@W0 + b0) @ W1 ; log_det = log|1 + (1-t^2)*(W0.W1)|
// z: [N,64] f32, W0: [64,1], b0: [1], W1: [1,64]
// d_out: x (N*64 floats) followed by log_det (N floats).
//
// Memory-bound (~541 MB traffic; float4-copy ceiling 6.29 TB/s -> ~86 us).
// 16 lanes per row, float4 per lane, shfl_xor butterfly for the row dot.
// R4: grid=2048 (exactly 8 blocks/CU resident = 32 waves, single shift),
// unroll x4 (4 independent loads batched per iteration).

typedef float f32x4 __attribute__((ext_vector_type(4)));

__global__ __launch_bounds__(256) void planar_flow_kernel(
    const float* __restrict__ z,
    const float* __restrict__ W0,
    const float* __restrict__ b0,
    const float* __restrict__ W1,
    float* __restrict__ x,
    float* __restrict__ log_det,
    int n_rows)
{
    const int tid    = blockIdx.x * blockDim.x + threadIdx.x;
    const int l      = threadIdx.x & 15;                    // lane within 16-group (column quad)
    const int g0     = tid >> 4;                            // starting row
    const int stride = (gridDim.x * blockDim.x) >> 4;       // rows per grid step

    const f32x4* __restrict__ z4 = reinterpret_cast<const f32x4*>(z);
    f32x4* __restrict__ x4       = reinterpret_cast<f32x4*>(x);

    // Per-thread W fragments (columns 4l..4l+3), loaded once (L1-resident).
    const f32x4 w0 = reinterpret_cast<const f32x4*>(W0)[l];
    const f32x4 w1 = reinterpret_cast<const f32x4*>(W1)[l];
    const float bias = b0[0];

    // s = W0 . W1 (scalar), reduced across the 16-lane group.
    float s = w0.x * w1.x + w0.y * w1.y + w0.z * w1.z + w0.w * w1.w;
    s += __shfl_xor(s, 1);
    s += __shfl_xor(s, 2);
    s += __shfl_xor(s, 4);
    s += __shfl_xor(s, 8);

    int row = g0;

    // Main loop: four independent rows in flight per thread.
    for (; row + 3 * stride < n_rows; row += 4 * stride) {
        const int i0 = (row + 0 * stride) * 16 + l;
        const int i1 = (row + 1 * stride) * 16 + l;
        const int i2 = (row + 2 * stride) * 16 + l;
        const int i3 = (row + 3 * stride) * 16 + l;

        const f32x4 zv0 = __builtin_nontemporal_load(z4 + i0);
        const f32x4 zv1 = __builtin_nontemporal_load(z4 + i1);
        const f32x4 zv2 = __builtin_nontemporal_load(z4 + i2);
        const f32x4 zv3 = __builtin_nontemporal_load(z4 + i3);

        float a0 = zv0.x * w0.x + zv0.y * w0.y + zv0.z * w0.z + zv0.w * w0.w;
        float a1 = zv1.x * w0.x + zv1.y * w0.y + zv1.z * w0.z + zv1.w * w0.w;
        float a2 = zv2.x * w0.x + zv2.y * w0.y + zv2.z * w0.z + zv2.w * w0.w;
        float a3 = zv3.x * w0.x + zv3.y * w0.y + zv3.z * w0.z + zv3.w * w0.w;
        a0 += __shfl_xor(a0, 1); a1 += __shfl_xor(a1, 1); a2 += __shfl_xor(a2, 1); a3 += __shfl_xor(a3, 1);
        a0 += __shfl_xor(a0, 2); a1 += __shfl_xor(a1, 2); a2 += __shfl_xor(a2, 2); a3 += __shfl_xor(a3, 2);
        a0 += __shfl_xor(a0, 4); a1 += __shfl_xor(a1, 4); a2 += __shfl_xor(a2, 4); a3 += __shfl_xor(a3, 4);
        a0 += __shfl_xor(a0, 8); a1 += __shfl_xor(a1, 8); a2 += __shfl_xor(a2, 8); a3 += __shfl_xor(a3, 8);
        a0 += bias; a1 += bias; a2 += bias; a3 += bias;

        const float t0 = 1.0f - 2.0f / (__expf(2.0f * a0) + 1.0f);
        const float t1 = 1.0f - 2.0f / (__expf(2.0f * a1) + 1.0f);
        const float t2 = 1.0f - 2.0f / (__expf(2.0f * a2) + 1.0f);
        const float t3 = 1.0f - 2.0f / (__expf(2.0f * a3) + 1.0f);

        f32x4 xv0, xv1, xv2, xv3;
        xv0.x = fmaf(t0, w1.x, zv0.x); xv0.y = fmaf(t0, w1.y, zv0.y);
        xv0.z = fmaf(t0, w1.z, zv0.z); xv0.w = fmaf(t0, w1.w, zv0.w);
        xv1.x = fmaf(t1, w1.x, zv1.x); xv1.y = fmaf(t1, w1.y, zv1.y);
        xv1.z = fmaf(t1, w1.z, zv1.z); xv1.w = fmaf(t1, w1.w, zv1.w);
        xv2.x = fmaf(t2, w1.x, zv2.x); xv2.y = fmaf(t2, w1.y, zv2.y);
        xv2.z = fmaf(t2, w1.z, zv2.z); xv2.w = fmaf(t2, w1.w, zv2.w);
        xv3.x = fmaf(t3, w1.x, zv3.x); xv3.y = fmaf(t3, w1.y, zv3.y);
        xv3.z = fmaf(t3, w1.z, zv3.z); xv3.w = fmaf(t3, w1.w, zv3.w);

        __builtin_nontemporal_store(xv0, x4 + i0);
        __builtin_nontemporal_store(xv1, x4 + i1);
        __builtin_nontemporal_store(xv2, x4 + i2);
        __builtin_nontemporal_store(xv3, x4 + i3);

        if (l == 0) {
            const float d0 = fmaf(1.0f - t0 * t0, s, 1.0f);
            const float d1 = fmaf(1.0f - t1 * t1, s, 1.0f);
            const float d2 = fmaf(1.0f - t2 * t2, s, 1.0f);
            const float d3 = fmaf(1.0f - t3 * t3, s, 1.0f);
            __builtin_nontemporal_store(__logf(fabsf(d0)), log_det + row + 0 * stride);
            __builtin_nontemporal_store(__logf(fabsf(d1)), log_det + row + 1 * stride);
            __builtin_nontemporal_store(__logf(fabsf(d2)), log_det + row + 2 * stride);
            __builtin_nontemporal_store(__logf(fabsf(d3)), log_det + row + 3 * stride);
        }
    }

    // Tail.
    for (; row < n_rows; row += stride) {
        const int idx = row * 16 + l;
        const f32x4 zv = __builtin_nontemporal_load(z4 + idx);

        float a = zv.x * w0.x + zv.y * w0.y + zv.z * w0.z + zv.w * w0.w;
        a += __shfl_xor(a, 1);
        a += __shfl_xor(a, 2);
        a += __shfl_xor(a, 4);
        a += __shfl_xor(a, 8);
        a += bias;

        const float t = 1.0f - 2.0f / (__expf(2.0f * a) + 1.0f);

        f32x4 xv;
        xv.x = fmaf(t, w1.x, zv.x);
        xv.y = fmaf(t, w1.y, zv.y);
        xv.z = fmaf(t, w1.z, zv.z);
        xv.w = fmaf(t, w1.w, zv.w);
        __builtin_nontemporal_store(xv, x4 + idx);

        if (l == 0) {
            const float det = fmaf(1.0f - t * t, s, 1.0f);
            __builtin_nontemporal_store(__logf(fabsf(det)), log_det + row);
        }
    }
}

extern "C" void kernel_launch(void* const* d_in, const int* in_sizes, int n_in,
                              void* d_out, int out_size, void* d_ws, size_t ws_size,
                              hipStream_t stream) {
    const float* z  = (const float*)d_in[0];
    const float* W0 = (const float*)d_in[1];
    const float* b0 = (const float*)d_in[2];
    const float* W1 = (const float*)d_in[3];

    const int n_rows = in_sizes[0] / 64;          // 1048576
    float* x       = (float*)d_out;               // [N,64]
    float* log_det = x + (size_t)n_rows * 64;     // [N]

    const int block = 256;
    const int grid  = 2048;                       // 8 blocks/CU resident, one shift
    planar_flow_kernel<<<grid, block, 0, stream>>>(z, W0, b0, W1, x, log_det, n_rows);
}

// Round 5
// 88.082 us; speedup vs baseline: 1.2889x; 1.2889x over previous
//
#include <hip/hip_runtime.h>

// PlanarFlow: x = z + tanh(z@W0 + b0) @ W1 ; log_det = log|1 + (1-t^2)*(W0.W1)|
// z: [N,64] f32, W0: [64,1], b0: [1], W1: [1,64]
// d_out: x (N*64 floats) followed by log_det (N floats).
//
// Memory-bound (~541 MB traffic). R5: flat launch — one row per 16-lane
// group, no grid-stride loop, grid=65536. Max TLP; minimal per-thread work.

typedef float f32x4 __attribute__((ext_vector_type(4)));

__global__ __launch_bounds__(256) void planar_flow_kernel(
    const float* __restrict__ z,
    const float* __restrict__ W0,
    const float* __restrict__ b0,
    const float* __restrict__ W1,
    float* __restrict__ x,
    float* __restrict__ log_det,
    int n_rows)
{
    const int tid = blockIdx.x * blockDim.x + threadIdx.x;
    const int l   = threadIdx.x & 15;          // lane within 16-group (column quad)
    const int row = tid >> 4;
    if (row >= n_rows) return;

    const f32x4* __restrict__ z4 = reinterpret_cast<const f32x4*>(z);
    f32x4* __restrict__ x4       = reinterpret_cast<f32x4*>(x);

    // Per-thread W fragments (columns 4l..4l+3), L1-resident.
    const f32x4 w0 = reinterpret_cast<const f32x4*>(W0)[l];
    const f32x4 w1 = reinterpret_cast<const f32x4*>(W1)[l];
    const float bias = b0[0];

    // s = W0 . W1 (scalar), reduced across the 16-lane group.
    float s = w0.x * w1.x + w0.y * w1.y + w0.z * w1.z + w0.w * w1.w;
    s += __shfl_xor(s, 1);
    s += __shfl_xor(s, 2);
    s += __shfl_xor(s, 4);
    s += __shfl_xor(s, 8);

    const int idx = row * 16 + l;
    const f32x4 zv = __builtin_nontemporal_load(z4 + idx);

    // a = z[row,:] . W0  (partial per lane, then 16-lane butterfly)
    float a = zv.x * w0.x + zv.y * w0.y + zv.z * w0.z + zv.w * w0.w;
    a += __shfl_xor(a, 1);
    a += __shfl_xor(a, 2);
    a += __shfl_xor(a, 4);
    a += __shfl_xor(a, 8);
    a += bias;

    // tanh(a) = 1 - 2/(exp(2a)+1); saturates correctly.
    const float t = 1.0f - 2.0f / (__expf(2.0f * a) + 1.0f);

    f32x4 xv;
    xv.x = fmaf(t, w1.x, zv.x);
    xv.y = fmaf(t, w1.y, zv.y);
    xv.z = fmaf(t, w1.z, zv.z);
    xv.w = fmaf(t, w1.w, zv.w);
    __builtin_nontemporal_store(xv, x4 + idx);

    if (l == 0) {
        const float det = fmaf(1.0f - t * t, s, 1.0f);
        __builtin_nontemporal_store(__logf(fabsf(det)), log_det + row);
    }
}

extern "C" void kernel_launch(void* const* d_in, const int* in_sizes, int n_in,
                              void* d_out, int out_size, void* d_ws, size_t ws_size,
                              hipStream_t stream) {
    const float* z  = (const float*)d_in[0];
    const float* W0 = (const float*)d_in[1];
    const float* b0 = (const float*)d_in[2];
    const float* W1 = (const float*)d_in[3];

    const int n_rows = in_sizes[0] / 64;          // 1048576
    float* x       = (float*)d_out;               // [N,64]
    float* log_det = x + (size_t)n_rows * 64;     // [N]

    const int block = 256;
    const int grid  = (n_rows * 16 + block - 1) / block;   // 65536: 1 row per 16 lanes
    planar_flow_kernel<<<grid, block, 0, stream>>>(z, W0, b0, W1, x, log_det, n_rows);
}

// Round 6
// 87.719 us; speedup vs baseline: 1.2942x; 1.0041x over previous
//
#include <hip/hip_runtime.h>

// PlanarFlow: x = z + tanh(z@W0 + b0) @ W1 ; log_det = log|1 + (1-t^2)*(W0.W1)|
// z: [N,64] f32, W0: [64,1], b0: [1], W1: [1,64]
// d_out: x (N*64 floats) followed by log_det (N floats).
//
// Memory-bound (~541 MB traffic). R5: flat launch — one row per 16-lane
// group, no grid-stride loop, grid=65536. Max TLP; minimal per-thread work.

typedef float f32x4 __attribute__((ext_vector_type(4)));

__global__ __launch_bounds__(256) void planar_flow_kernel(
    const float* __restrict__ z,
    const float* __restrict__ W0,
    const float* __restrict__ b0,
    const float* __restrict__ W1,
    float* __restrict__ x,
    float* __restrict__ log_det,
    int n_rows)
{
    const int tid = blockIdx.x * blockDim.x + threadIdx.x;
    const int l   = threadIdx.x & 15;          // lane within 16-group (column quad)
    const int row = tid >> 4;
    if (row >= n_rows) return;

    const f32x4* __restrict__ z4 = reinterpret_cast<const f32x4*>(z);
    f32x4* __restrict__ x4       = reinterpret_cast<f32x4*>(x);

    // Per-thread W fragments (columns 4l..4l+3), L1-resident.
    const f32x4 w0 = reinterpret_cast<const f32x4*>(W0)[l];
    const f32x4 w1 = reinterpret_cast<const f32x4*>(W1)[l];
    const float bias = b0[0];

    // s = W0 . W1 (scalar), reduced across the 16-lane group.
    float s = w0.x * w1.x + w0.y * w1.y + w0.z * w1.z + w0.w * w1.w;
    s += __shfl_xor(s, 1);
    s += __shfl_xor(s, 2);
    s += __shfl_xor(s, 4);
    s += __shfl_xor(s, 8);

    const int idx = row * 16 + l;
    const f32x4 zv = __builtin_nontemporal_load(z4 + idx);

    // a = z[row,:] . W0  (partial per lane, then 16-lane butterfly)
    float a = zv.x * w0.x + zv.y * w0.y + zv.z * w0.z + zv.w * w0.w;
    a += __shfl_xor(a, 1);
    a += __shfl_xor(a, 2);
    a += __shfl_xor(a, 4);
    a += __shfl_xor(a, 8);
    a += bias;

    // tanh(a) = 1 - 2/(exp(2a)+1); saturates correctly.
    const float t = 1.0f - 2.0f / (__expf(2.0f * a) + 1.0f);

    f32x4 xv;
    xv.x = fmaf(t, w1.x, zv.x);
    xv.y = fmaf(t, w1.y, zv.y);
    xv.z = fmaf(t, w1.z, zv.z);
    xv.w = fmaf(t, w1.w, zv.w);
    __builtin_nontemporal_store(xv, x4 + idx);

    if (l == 0) {
        const float det = fmaf(1.0f - t * t, s, 1.0f);
        __builtin_nontemporal_store(__logf(fabsf(det)), log_det + row);
    }
}

extern "C" void kernel_launch(void* const* d_in, const int* in_sizes, int n_in,
                              void* d_out, int out_size, void* d_ws, size_t ws_size,
                              hipStream_t stream) {
    const float* z  = (const float*)d_in[0];
    const float* W0 = (const float*)d_in[1];
    const float* b0 = (const float*)d_in[2];
    const float* W1 = (const float*)d_in[3];

    const int n_rows = in_sizes[0] / 64;          // 1048576
    float* x       = (float*)d_out;               // [N,64]
    float* log_det = x + (size_t)n_rows * 64;     // [N]

    const int block = 256;
    const int grid  = (n_rows * 16 + block - 1) / block;   // 65536: 1 row per 16 lanes
    planar_flow_kernel<<<grid, block, 0, stream>>>(z, W0, b0, W1, x, log_det, n_rows);
}